// Round 1
// baseline (1464.330 us; speedup 1.0000x reference)
//
#include <hip/hip_runtime.h>
#include <stdint.h>

// TriVec scoring + LSE loss, MI355X.
// Identities used:
//   obj_scores[b,v]  = sum_{i,k} sp[b,2-i,k] * emb[v,i,k]   (fold reversal into A)
//   subj_scores[b,v] = sum_{i,k} po[b,i,k]   * emb[v,i,k]
//   excluded entries obj_scores[b,obj_b] == subj_scores[b,subj_b] == scores[b]
//   -> lse = log(sum_v exp(x) - exp(scores[b]))  (scores tiny, no max-shift needed)

#define V_SIZE 500000
#define EK 384           // 3*128, row length of embeddings
#define BATCH 256
#define LAMB 0.01f
#define CH 512           // v-chunk per workgroup

typedef __attribute__((ext_vector_type(8))) __bf16 bf16x8;
typedef __attribute__((ext_vector_type(16))) float f32x16;

// ws layout (bytes):
//   [0,       196608) A_obj  bf16 [256][384]
//   [196608,  393216) A_subj bf16 [256][384]
//   [393216,  425984) accbuf float[512*16]  (64B stride per row to avoid atomic line contention)
//   [425984,  427008) regbuf float[256]

__device__ __forceinline__ unsigned short f2bf(float f) {
    unsigned u = __builtin_bit_cast(unsigned, f);
    unsigned r = u + 0x7FFFu + ((u >> 16) & 1u);   // RNE
    return (unsigned short)(r >> 16);
}

// ---------------- kernel 1: gather, build A matrices, scores, reg ----------------
__global__ __launch_bounds__(384) void k_prep(
    const float* __restrict__ emb, const int* __restrict__ sidx,
    const int* __restrict__ pidx, const int* __restrict__ oidx,
    float* __restrict__ out, unsigned short* __restrict__ Aobj,
    unsigned short* __restrict__ Asubj, float* __restrict__ accbuf,
    float* __restrict__ regbuf)
{
    int b = blockIdx.x;
    int t = threadIdx.x;          // 0..383 = i*128 + k
    if (b == 0) {                 // zero the 512x16 accumulator region
        for (int j = t; j < 512 * 16; j += 384) accbuf[j] = 0.0f;
    }
    int i  = t >> 7;
    int k  = t & 127;
    int ri = 2 - i;
    size_t sb = (size_t)sidx[b] * EK;
    size_t pb = (size_t)pidx[b] * EK;
    size_t ob = (size_t)oidx[b] * EK;
    float sv  = emb[sb + t];
    float pv  = emb[pb + t];
    float ov  = emb[ob + t];
    float orv = emb[ob + (size_t)ri * 128 + k];   // o_rev at (i,k)
    float sp  = sv * pv;
    // A_obj[b][2-i][k] = sp[b][i][k]
    Aobj [(size_t)b * EK + (size_t)ri * 128 + k] = f2bf(sp);
    // A_subj[b][i][k] = p[i][k]*o_rev[i][k]
    Asubj[(size_t)b * EK + t] = f2bf(pv * orv);
    float scorep = sp * orv;
    float regp = fabsf(sv) * sv * sv + fabsf(pv) * pv * pv + fabsf(ov) * ov * ov;

    __shared__ float red[2][6];
    float v1 = scorep, v2 = regp;
    #pragma unroll
    for (int off = 32; off > 0; off >>= 1) {
        v1 += __shfl_down(v1, off);
        v2 += __shfl_down(v2, off);
    }
    int wid = t >> 6;
    if ((t & 63) == 0) { red[0][wid] = v1; red[1][wid] = v2; }
    __syncthreads();
    if (t == 0) {
        float s1 = 0.f, s2 = 0.f;
        #pragma unroll
        for (int w = 0; w < 6; ++w) { s1 += red[0][w]; s2 += red[1][w]; }
        out[b]    = s1;    // scores[b], fp32-exact
        regbuf[b] = s2;
    }
}

// ---------------- kernel 2: fused GEMM + sum-of-exp over V ----------------
// grid.x = 2*nchunk; even wgid -> obj rows (accbuf[0..255]), odd -> subj (256..511).
// Pairs (2c,2c+1) stream the same E chunk -> second reader hits LLC.
__global__ __launch_bounds__(512, 2) void k_main(
    const float* __restrict__ emb, const unsigned short* __restrict__ Aobj,
    const unsigned short* __restrict__ Asubj, float* __restrict__ accbuf)
{
    __shared__ __align__(16) unsigned short etile[64 * EK];   // 48 KiB, XOR-swizzled

    int wgid  = blockIdx.x;
    int role  = wgid & 1;
    int chunk = wgid >> 1;
    int vstart = chunk * CH;
    int vend   = min(vstart + CH, V_SIZE);
    const unsigned short* A = role ? Asubj : Aobj;

    int tid  = threadIdx.x;
    int wave = tid >> 6;
    int lane = tid & 63;
    int l31  = lane & 31;
    int lhi  = lane >> 5;   // 0/1

    // A fragments, register-resident: wave owns rows [wave*32, wave*32+32)
    // 32x32x16 A layout: row = lane&31, k = (lane>>5)*8 + e
    bf16x8 a[24];
    {
        int row = wave * 32 + l31;
        const unsigned short* ap = A + (size_t)row * EK + lhi * 8;
        #pragma unroll
        for (int ks = 0; ks < 24; ++ks)
            a[ks] = *reinterpret_cast<const bf16x8*>(ap + ks * 16);
    }

    float runsum[16];
    #pragma unroll
    for (int r = 0; r < 16; ++r) runsum[r] = 0.0f;

    float4 stg[12];  // prefetch registers (T14 async-stage split)

    auto load_tile = [&](int vb0) {
        #pragma unroll
        for (int j = 0; j < 12; ++j) {
            int fidx = j * 512 + tid;         // float4 index within 64x384 tile
            int row  = fidx / 96;             // 96 float4 per row
            if (vb0 + row < V_SIZE) {
                stg[j] = *reinterpret_cast<const float4*>(emb + (size_t)vb0 * EK + (size_t)fidx * 4);
            } else {
                stg[j] = make_float4(0.f, 0.f, 0.f, 0.f);
            }
        }
    };
    auto store_tile = [&]() {
        #pragma unroll
        for (int j = 0; j < 12; ++j) {
            int fidx = j * 512 + tid;
            int row  = fidx / 96;
            unsigned w  = (unsigned)fidx * 8u;
            unsigned sw = w ^ ((unsigned)(row & 7) << 4) ^ ((unsigned)((row >> 3) & 1) << 7);
            ushort4 pk;
            pk.x = f2bf(stg[j].x); pk.y = f2bf(stg[j].y);
            pk.z = f2bf(stg[j].z); pk.w = f2bf(stg[j].w);
            *reinterpret_cast<ushort4*>(reinterpret_cast<char*>(etile) + sw) = pk;
        }
    };
    auto read_b = [&](int vb, int ks) -> bf16x8 {
        // B layout: col = lane&31 (v within block), k = (lane>>5)*8 + e
        int vrow = vb * 32 + l31;
        unsigned r  = (unsigned)vrow * 768u + (unsigned)ks * 32u + (unsigned)lhi * 16u;
        unsigned sw = r ^ ((unsigned)(vrow & 7) << 4) ^ ((unsigned)((vrow >> 3) & 1) << 7);
        return *reinterpret_cast<const bf16x8*>(reinterpret_cast<const char*>(etile) + sw);
    };

    load_tile(vstart);
    for (int vb0 = vstart; vb0 < vend; vb0 += 64) {
        __syncthreads();       // previous tile's LDS reads complete
        store_tile();
        __syncthreads();
        int nxt = vb0 + 64;
        if (nxt < vend) load_tile(nxt);   // in flight under MFMA phase

        f32x16 acc0, acc1;
        #pragma unroll
        for (int r = 0; r < 16; ++r) { acc0[r] = 0.f; acc1[r] = 0.f; }
        #pragma unroll
        for (int ks = 0; ks < 24; ++ks) {
            bf16x8 b0 = read_b(0, ks);
            bf16x8 b1 = read_b(1, ks);
            acc0 = __builtin_amdgcn_mfma_f32_32x32x16_bf16(a[ks], b0, acc0, 0, 0, 0);
            acc1 = __builtin_amdgcn_mfma_f32_32x32x16_bf16(a[ks], b1, acc1, 0, 0, 0);
        }
        // online sum-of-exp; C/D layout: col = lane&31, row = (r&3)+8*(r>>2)+4*(lane>>5)
        bool m0 = (vb0 + l31)      < V_SIZE;
        bool m1 = (vb0 + 32 + l31) < V_SIZE;
        #pragma unroll
        for (int r = 0; r < 16; ++r) {
            runsum[r] += (m0 ? __expf(acc0[r]) : 0.0f);
            runsum[r] += (m1 ? __expf(acc1[r]) : 0.0f);
        }
    }

    // reduce over the 32 columns (lanes within each 32-half)
    #pragma unroll
    for (int r = 0; r < 16; ++r) {
        float v = runsum[r];
        v += __shfl_xor(v, 1);
        v += __shfl_xor(v, 2);
        v += __shfl_xor(v, 4);
        v += __shfl_xor(v, 8);
        v += __shfl_xor(v, 16);
        runsum[r] = v;
    }
    if (l31 == 0) {
        #pragma unroll
        for (int r = 0; r < 16; ++r) {
            int rowl = (r & 3) + 8 * (r >> 2) + 4 * lhi;
            int row  = wave * 32 + rowl;
            atomicAdd(&accbuf[(size_t)(role * 256 + row) * 16], runsum[r]);
        }
    }
}

// ---------------- kernel 3: assemble loss ----------------
__global__ __launch_bounds__(256) void k_final(
    float* __restrict__ out, const float* __restrict__ accbuf,
    const float* __restrict__ regbuf)
{
    int b = threadIdx.x;
    float sc = out[b];
    float So = accbuf[(size_t)b * 16];
    float Ss = accbuf[(size_t)(256 + b) * 16];
    float e  = expf(sc);
    float val = -2.0f * sc + logf(So - e) + logf(Ss - e) + (LAMB / 3.0f) * regbuf[b];
    __shared__ float red[4];
    #pragma unroll
    for (int off = 32; off > 0; off >>= 1) val += __shfl_down(val, off);
    if ((b & 63) == 0) red[b >> 6] = val;
    __syncthreads();
    if (b == 0) out[256] = red[0] + red[1] + red[2] + red[3];
}

extern "C" void kernel_launch(void* const* d_in, const int* in_sizes, int n_in,
                              void* d_out, int out_size, void* d_ws, size_t ws_size,
                              hipStream_t stream)
{
    const float* emb = (const float*)d_in[0];
    const int* sidx  = (const int*)d_in[1];
    const int* pidx  = (const int*)d_in[2];
    const int* oidx  = (const int*)d_in[3];
    float* out = (float*)d_out;
    char* ws = (char*)d_ws;
    unsigned short* Aobj  = (unsigned short*)(ws);
    unsigned short* Asubj = (unsigned short*)(ws + 196608);
    float* accbuf = (float*)(ws + 393216);
    float* regbuf = (float*)(ws + 425984);

    k_prep<<<BATCH, 384, 0, stream>>>(emb, sidx, pidx, oidx, out, Aobj, Asubj, accbuf, regbuf);
    int nchunk = (V_SIZE + CH - 1) / CH;
    k_main<<<nchunk * 2, 512, 0, stream>>>(emb, Aobj, Asubj, accbuf);
    k_final<<<1, 256, 0, stream>>>(out, accbuf, regbuf);
}